// Round 6
// baseline (187.382 us; speedup 1.0000x reference)
//
#include <hip/hip_runtime.h>
#include <cstdint>

// ---------------------------------------------------------------------------
// CTC loss pipeline (3 launches):
//   k_gemm : reads x,W fp32 DIRECTLY, converts bf16 in-reg while staging to
//            LDS (W transposed in the register repack), m97-style BK=64 MFMA
//            loop, bf16 logits out, zeroes d_out.
//   k_softmax_gather : row lse + ext-label exp-gather -> pext (linear domain)
//   k_ctc  : 4-deep pipelined scaled linear-domain CTC forward, atomic mean.
// ---------------------------------------------------------------------------

#define SPAD 260                      // padded extended-state row (257 -> 260)
#define PEXT_PAD_ROWS 64              // prefetch overrun pad (loaded, never consumed)
#define LSTR 66                       // LDS tile row stride in ushorts (64 + 2 pad)
#define L2E 1.4426950408889634f
#define LN2 0.6931471805599453f

typedef short v8s __attribute__((ext_vector_type(8)));
typedef float v4f __attribute__((ext_vector_type(4)));

__device__ __forceinline__ uint32_t f2bf_bits(float f) {
  uint32_t u = __float_as_uint(f);
  return (u + 0x7FFFu + ((u >> 16) & 1u)) >> 16;   // RNE
}
__device__ __forceinline__ float bf2f(uint32_t h) { return __uint_as_float(h << 16); }

// ---------------- k_gemm: fused convert + m97 GEMM, BK=64, bf16 out ----------------
// logits[m][n] = sum_k x[m][k] * W[k][n] + bias[n]
__global__ __launch_bounds__(256) void k_gemm(const float* __restrict__ x,
                                              const float* __restrict__ W,
                                              const float* __restrict__ bias,
                                              uint16_t* __restrict__ C,
                                              float* __restrict__ out,
                                              int M, int N, int K) {
  __shared__ uint16_t As[128 * LSTR];   // A[r][k] bf16, r=0..127, k=0..63
  __shared__ uint16_t Bs[128 * LSTR];   // B[n][k] bf16 (transposed W)
  const int tid = threadIdx.x, lane = tid & 63, wave = tid >> 6;
  const int m0 = blockIdx.x * 128, n0 = blockIdx.y * 128;
  if (blockIdx.x == 0 && blockIdx.y == 0 && tid == 0) out[0] = 0.f;  // zero atomic target
  const int wm = wave & 1, wn = wave >> 1;
  const int frow = lane & 15, kb = lane >> 4;
  // A staging: thread -> (row, k-half);  B staging: thread -> (8 k's, 4 n's)
  const int ar = tid >> 1, ak = (tid & 1) * 32;
  const int bk = (tid >> 5) * 8, bn = (tid & 31) * 4;
  v4f acc[4][4] = {};

  for (int k0 = 0; k0 < K; k0 += 64) {
    float4 av[8], wv[8];
    #pragma unroll
    for (int j = 0; j < 8; j++) av[j] = *(const float4*)(x + (size_t)(m0 + ar) * K + k0 + ak + 4 * j);
    #pragma unroll
    for (int j = 0; j < 8; j++) wv[j] = *(const float4*)(W + (size_t)(k0 + bk + j) * N + n0 + bn);

    __syncthreads();   // protect LDS from previous iteration's readers
    #pragma unroll
    for (int j = 0; j < 4; j++) {      // A: 32 bf16, k-contiguous
      union { v8s v; uint16_t s[8]; } p;
      #pragma unroll
      for (int e = 0; e < 4; e++) {
        p.s[2 * e]     = (uint16_t)f2bf_bits(((const float*)&av[2 * j])[e]);
        p.s[2 * e + 1] = 0;  // placeholder, overwritten below
      }
      // pack av[2j] (k: 8j..8j+3) and av[2j+1] (k: 8j+4..8j+7)
      p.s[0] = (uint16_t)f2bf_bits(av[2 * j].x);  p.s[1] = (uint16_t)f2bf_bits(av[2 * j].y);
      p.s[2] = (uint16_t)f2bf_bits(av[2 * j].z);  p.s[3] = (uint16_t)f2bf_bits(av[2 * j].w);
      p.s[4] = (uint16_t)f2bf_bits(av[2 * j + 1].x); p.s[5] = (uint16_t)f2bf_bits(av[2 * j + 1].y);
      p.s[6] = (uint16_t)f2bf_bits(av[2 * j + 1].z); p.s[7] = (uint16_t)f2bf_bits(av[2 * j + 1].w);
      *(v8s*)(As + ar * LSTR + ak + 8 * j) = p.v;
    }
    #pragma unroll
    for (int i = 0; i < 4; i++) {      // B: transpose repack, 8 k's for n=bn+i
      union { v8s v; uint16_t s[8]; } p;
      #pragma unroll
      for (int j = 0; j < 8; j++) p.s[j] = (uint16_t)f2bf_bits(((const float*)&wv[j])[i]);
      *(v8s*)(Bs + (bn + i) * LSTR + bk) = p.v;
    }
    __syncthreads();

    #pragma unroll
    for (int t = 0; t < 2; t++) {
      v8s af[4], bf[4];
      #pragma unroll
      for (int i = 0; i < 4; i++)
        af[i] = *(const v8s*)(As + (wm * 64 + i * 16 + frow) * LSTR + t * 32 + kb * 8);
      #pragma unroll
      for (int j = 0; j < 4; j++)
        bf[j] = *(const v8s*)(Bs + (wn * 64 + j * 16 + frow) * LSTR + t * 32 + kb * 8);
      #pragma unroll
      for (int i = 0; i < 4; i++)
        #pragma unroll
        for (int j = 0; j < 4; j++)
          acc[i][j] = __builtin_amdgcn_mfma_f32_16x16x32_bf16(af[i], bf[j], acc[i][j], 0, 0, 0);
    }
  }

  // epilogue: C/D layout col=lane&15, row=(lane>>4)*4+reg  [m89-verified]
  const int crow = (lane >> 4) * 4, ccol = lane & 15;
  #pragma unroll
  for (int j = 0; j < 4; j++) {
    const int n = n0 + wn * 64 + j * 16 + ccol;
    const float bv = bias[n];
    #pragma unroll
    for (int i = 0; i < 4; i++) {
      const int mb = m0 + wm * 64 + i * 16 + crow;
      #pragma unroll
      for (int r2 = 0; r2 < 4; r2++)
        C[(size_t)(mb + r2) * N + n] = (uint16_t)f2bf_bits(acc[i][j][r2] + bv);
    }
  }
}

// ---------------- k_softmax_gather: row lse + gather (linear domain) ----------------
__global__ void k_softmax_gather(const uint16_t* __restrict__ logits, const int* __restrict__ target,
                                 const int* __restrict__ tlen, float* __restrict__ pext,
                                 int T, int V, int L) {
  const int row = blockIdx.x * 4 + (threadIdx.x >> 6);   // one wave per row
  const int lane = threadIdx.x & 63;
  const uint16_t* lrow = logits + (size_t)row * V;

  float xs[16];
  int cnt = 0;
  float mx = -INFINITY;
  for (int base = 0; base < V; base += 256) {
    const int idx = base + lane * 4;
    uint2 u = *(const uint2*)(lrow + idx);
    float4 v;
    v.x = bf2f(u.x & 0xFFFFu); v.y = bf2f(u.x >> 16);
    v.z = bf2f(u.y & 0xFFFFu); v.w = bf2f(u.y >> 16);
    xs[cnt] = v.x; xs[cnt + 1] = v.y; xs[cnt + 2] = v.z; xs[cnt + 3] = v.w; cnt += 4;
    mx = fmaxf(mx, fmaxf(fmaxf(v.x, v.y), fmaxf(v.z, v.w)));
  }
  #pragma unroll
  for (int off = 32; off; off >>= 1) mx = fmaxf(mx, __shfl_xor(mx, off, 64));
  float sum = 0.f;
  #pragma unroll
  for (int q = 0; q < 16; q++) { if (q < cnt) sum += exp2f((xs[q] - mx) * L2E); }
  #pragma unroll
  for (int off = 32; off; off >>= 1) sum += __shfl_xor(sum, off, 64);
  const float lse2 = mx * L2E + log2f(sum);

  const int bidx = row / T;
  const int Lb = tlen[bidx];
  const int S = 2 * Lb + 1;
  float* prow = pext + (size_t)row * SPAD;
  for (int s = lane; s < SPAD; s += 64) {
    float p = 0.f;
    if (s < S) {
      const int lbl = (s & 1) ? target[bidx * L + ((s - 1) >> 1)] : 0;
      p = exp2f(bf2f(lrow[lbl]) * L2E - lse2);
    }
    prow[s] = p;
  }
}

// ---------------- k_ctc: scaled linear-domain CTC forward, 1 wave per batch ----------------
__device__ __forceinline__ float wave_shr1(float x) {   // lane l <- lane l-1, lane0 <- 0
  return __int_as_float(__builtin_amdgcn_update_dpp(0, __float_as_int(x), 0x138, 0xf, 0xf, true));
}
__device__ __forceinline__ float wave_max_nonneg(float x) {
  x = fmaxf(x, __int_as_float(__builtin_amdgcn_update_dpp(0, __float_as_int(x), 0x111, 0xf, 0xf, true)));
  x = fmaxf(x, __int_as_float(__builtin_amdgcn_update_dpp(0, __float_as_int(x), 0x112, 0xf, 0xf, true)));
  x = fmaxf(x, __int_as_float(__builtin_amdgcn_update_dpp(0, __float_as_int(x), 0x114, 0xf, 0xf, true)));
  x = fmaxf(x, __int_as_float(__builtin_amdgcn_update_dpp(0, __float_as_int(x), 0x118, 0xf, 0xf, true)));
  x = fmaxf(x, __int_as_float(__builtin_amdgcn_update_dpp(0, __float_as_int(x), 0x142, 0xf, 0xf, true)));
  x = fmaxf(x, __int_as_float(__builtin_amdgcn_update_dpp(0, __float_as_int(x), 0x143, 0xf, 0xf, true)));
  return __int_as_float(__builtin_amdgcn_readlane(__float_as_int(x), 63));
}

__device__ __forceinline__ void load8(float4* __restrict__ p, float* __restrict__ p4,
                                      const float* __restrict__ pb, int t0, int lane) {
  #pragma unroll
  for (int k = 0; k < 8; k++) {
    const float* row = pb + (size_t)(t0 + k) * SPAD;
    p[k] = *(const float4*)(row + (lane << 2));
    p4[k] = row[256];               // wave-broadcast load
  }
}

__global__ __launch_bounds__(64, 1) void k_ctc(const float* __restrict__ pext,
                                               const int* __restrict__ target,
                                               const int* __restrict__ ilen,
                                               const int* __restrict__ tlen,
                                               float* __restrict__ out, int T, int L) {
  const int b = blockIdx.x;
  const int lane = threadIdx.x;          // 64 threads = 1 wave
  const int B = gridDim.x;
  const int Tb = ilen[b];
  const int Lb = tlen[b];
  const int S = 2 * Lb + 1;
  const int* tg = target + b * L;

  const int s1 = 4 * lane + 1, s3 = 4 * lane + 3;
  float sk1 = 0.f, sk3 = 0.f;
  if (s1 >= 3 && s1 < S) sk1 = (tg[(s1 - 1) >> 1] != tg[(s1 - 3) >> 1]) ? 1.f : 0.f;
  if (s3 >= 3 && s3 < S) sk3 = (tg[(s3 - 1) >> 1] != tg[(s3 - 3) >> 1]) ? 1.f : 0.f;

  const float* pb = pext + (size_t)b * T * SPAD;
  const float4 p0 = *(const float4*)(pb + (lane << 2));
  float a0 = (lane == 0) ? p0.x : 0.f;
  float a1 = (lane == 0) ? p0.y : 0.f;
  float a2 = 0.f, a3 = 0.f, a4 = 0.f;
  float log2C = 0.f;

  #define CTC_STEP(PP, P4) {                                            \
    const float pm3 = wave_shr1(a3);                                    \
    const float a255 = __int_as_float(__builtin_amdgcn_readlane(__float_as_int(a3), 63)); \
    const float n0v = (a0 + pm3) * (PP).x;                              \
    const float n1v = (a1 + a0 + sk1 * pm3) * (PP).y;                   \
    const float n2v = (a2 + a1) * (PP).z;                               \
    const float n3v = (a3 + a2 + sk3 * a1) * (PP).w;                    \
    const float n4v = (a4 + a255) * (P4);                               \
    a0 = n0v; a1 = n1v; a2 = n2v; a3 = n3v; a4 = n4v; }

  #define RENORM {                                                      \
    float m = fmaxf(fmaxf(fmaxf(a0, a1), fmaxf(a2, a3)), a4);           \
    m = wave_max_nonneg(m);                                             \
    const int e = (int)((__float_as_uint(m) >> 23) & 255u) - 127;       \
    const float scale = __uint_as_float((uint32_t)(127 - e) << 23);     \
    a0 *= scale; a1 *= scale; a2 *= scale; a3 *= scale; a4 *= scale;    \
    log2C += (float)e; }

  float4 Pa[8], Pb_[8], Pc[8], Pd[8];
  float Qa[8], Qb[8], Qc[8], Qd[8];
  int t0 = 1;
  bool done = false;
  load8(Pa, Qa, pb, t0, lane);
  load8(Pb_, Qb, pb, t0 + 8, lane);
  load8(Pc, Qc, pb, t0 + 16, lane);
  __builtin_amdgcn_sched_barrier(0);

  #define PHASE(LP, LQ, CP, CQ) {                                       \
    if (t0 + 8 <= Tb) {                                                 \
      load8(LP, LQ, pb, t0 + 24, lane);                                 \
      __builtin_amdgcn_sched_barrier(0);                                \
      _Pragma("unroll")                                                 \
      for (int k = 0; k < 8; k++) CTC_STEP(CP[k], CQ[k]);               \
      RENORM; t0 += 8;                                                  \
    } else {                                                            \
      _Pragma("unroll")                                                 \
      for (int k = 0; k < 8; k++) { if (t0 + k < Tb) CTC_STEP(CP[k], CQ[k]); } \
      RENORM; done = true;                                              \
    } }

  while (!done) {
    PHASE(Pd, Qd, Pa, Qa); if (done) break;
    PHASE(Pa, Qa, Pb_, Qb); if (done) break;
    PHASE(Pb_, Qb, Pc, Qc); if (done) break;
    PHASE(Pc, Qc, Pd, Qd);
  }

  __shared__ float abuf[257];
  abuf[4 * lane + 0] = a0; abuf[4 * lane + 1] = a1;
  abuf[4 * lane + 2] = a2; abuf[4 * lane + 3] = a3;
  if (lane == 63) abuf[256] = a4;
  __syncthreads();
  if (lane == 0) {
    const float ssum = abuf[2 * Lb - 1] + abuf[2 * Lb];
    const float ll = (log2f(ssum) + log2C) * LN2;
    float nll = -ll;
    if (!(nll < 1e29f)) nll = 0.f;                 // zero_infinity (also catches inf/nan)
    atomicAdd(out, nll / ((float)(Lb > 0 ? Lb : 1) * (float)B));
  }
}

// ---------------------------------------------------------------------------
extern "C" void kernel_launch(void* const* d_in, const int* in_sizes, int n_in,
                              void* d_out, int out_size, void* d_ws, size_t ws_size,
                              hipStream_t stream) {
  const float* x      = (const float*)d_in[0];
  const float* W      = (const float*)d_in[1];
  const float* bias   = (const float*)d_in[2];
  const int*  target  = (const int*)d_in[3];
  const int*  ilen    = (const int*)d_in[4];
  const int*  tlen    = (const int*)d_in[5];

  const int B = in_sizes[4];
  const int V = in_sizes[2];
  const int D = in_sizes[1] / V;
  const int T = in_sizes[0] / (B * D);
  const int L = in_sizes[3] / B;
  const int M = B * T;

  char* ws = (char*)d_ws;
  uint16_t* logits = (uint16_t*)ws;
  const size_t log_bytes = (size_t)M * V * 2;
  float* pext = (float*)(ws + log_bytes);

  k_gemm<<<dim3(M / 128, V / 128), 256, 0, stream>>>(x, W, bias, logits, (float*)d_out, M, V, D);
  k_softmax_gather<<<M / 4, 256, 0, stream>>>(logits, target, tlen, pext, T, V, L);
  k_ctc<<<B, 64, 0, stream>>>(pext, target, ilen, tlen, (float*)d_out, T, L);
}

// Round 7
// 186.214 us; speedup vs baseline: 1.0063x; 1.0063x over previous
//
#include <hip/hip_runtime.h>
#include <cstdint>

// ---------------------------------------------------------------------------
// CTC loss pipeline:
//   k_prep : x fp32->bf16, W[D,V] -> Wt[V,D] bf16, zero d_out
//   k_gemm : A via global_load_lds (LDS), B fragments DIRECT from global/L2
//            (Wt is 1 MB, L2-resident, frag reads are wave-coalesced).
//            BK=64, bf16 logits out.
//   k_softmax_gather : row lse + ext-label exp-gather -> pext (linear domain)
//   k_ctc  : 4-deep pipelined scaled linear-domain CTC forward, atomic mean.
// ---------------------------------------------------------------------------

#define SPAD 260                      // padded extended-state row (257 -> 260)
#define PEXT_PAD_ROWS 64              // prefetch overrun pad (loaded, never consumed)
#define L2E 1.4426950408889634f
#define LN2 0.6931471805599453f

typedef short v8s __attribute__((ext_vector_type(8)));
typedef float v4f __attribute__((ext_vector_type(4)));

__device__ __forceinline__ uint32_t f2bf_bits(float f) {
  uint32_t u = __float_as_uint(f);
  return (u + 0x7FFFu + ((u >> 16) & 1u)) >> 16;   // RNE
}
__device__ __forceinline__ float bf2f(uint32_t h) { return __uint_as_float(h << 16); }

// ---------------- k_prep: x fp32->bf16, W transpose->bf16, zero d_out ----------------
__global__ void k_prep(const float* __restrict__ x, uint16_t* __restrict__ xb, long long n,
                       const float* __restrict__ W, uint16_t* __restrict__ Wt, int D, int V,
                       float* __restrict__ out, int nconv) {
  if (blockIdx.x == 0 && threadIdx.x == 0) out[0] = 0.f;   // zero the atomic target
  if ((int)blockIdx.x < nconv) {
    long long i = ((long long)blockIdx.x * blockDim.x + threadIdx.x) * 8;
    if (i >= n) return;
    float4 a = *(const float4*)(x + i);
    float4 b = *(const float4*)(x + i + 4);
    uint4 o;
    o.x = f2bf_bits(a.x) | (f2bf_bits(a.y) << 16);
    o.y = f2bf_bits(a.z) | (f2bf_bits(a.w) << 16);
    o.z = f2bf_bits(b.x) | (f2bf_bits(b.y) << 16);
    o.w = f2bf_bits(b.z) | (f2bf_bits(b.w) << 16);
    *(uint4*)(xb + i) = o;
  } else {
    __shared__ float tile[32][33];
    const int bid2 = blockIdx.x - nconv;
    const int n0 = (bid2 % (V / 32)) * 32, k0 = (bid2 / (V / 32)) * 32;
    const int tx = threadIdx.x & 31, ty = threadIdx.x >> 5;   // (32,8)
    #pragma unroll
    for (int i = 0; i < 32; i += 8)
      tile[ty + i][tx] = W[(size_t)(k0 + ty + i) * V + n0 + tx];
    __syncthreads();
    #pragma unroll
    for (int i = 0; i < 32; i += 8)
      Wt[(size_t)(n0 + ty + i) * D + k0 + tx] = (uint16_t)f2bf_bits(tile[tx][ty + i]);
  }
}

// ---------------- k_gemm: A via LDS, B direct from global/L2, BK=64 ----------------
// A:[M,K] bf16, Bt:[N,K] bf16 (=W^T), C:[M,N] bf16.
__global__ __launch_bounds__(256) void k_gemm(const uint16_t* __restrict__ A,
                                              const uint16_t* __restrict__ Bt,
                                              const float* __restrict__ bias,
                                              uint16_t* __restrict__ C, int M, int N, int K) {
  __shared__ uint16_t As[2][128 * 32];   // [k-half][row*32 + k] — 16 KB total
  const int tid = threadIdx.x, lane = tid & 63, wave = tid >> 6;
  const int m0 = blockIdx.x * 128, n0 = blockIdx.y * 128;
  const int wm = wave & 1, wn = wave >> 1;
  const int frow = lane & 15, kb = lane >> 4;
  const int lr = lane >> 2, kc = lane & 3;
  v4f acc[4][4] = {};

  for (int k0 = 0; k0 < K; k0 += 64) {
    __syncthreads();   // protect LDS from previous iteration's readers
    #pragma unroll
    for (int t = 0; t < 2; t++)
      #pragma unroll
      for (int i = 0; i < 2; i++) {
        const int r = (wave * 2 + i) * 16 + lr;
        const uint16_t* ga = A + (size_t)(m0 + r) * K + k0 + t * 32 + kc * 8;
        __builtin_amdgcn_global_load_lds(
            (const __attribute__((address_space(1))) void*)ga,
            (__attribute__((address_space(3))) void*)(&As[t][0] + (wave * 2 + i) * 512 + lane * 8), 16, 0, 0);
      }
    // B fragments: direct global loads (L2-resident Wt), issued as a batch so
    // their latency overlaps the A-drain + ds_reads. Wave-coalesced: 16 lanes
    // x 16B = 16 full 64B lines per instruction.
    v8s bfr[2][4];
    #pragma unroll
    for (int t = 0; t < 2; t++)
      #pragma unroll
      for (int j = 0; j < 4; j++)
        bfr[t][j] = *(const v8s*)(Bt + (size_t)(n0 + wn * 64 + j * 16 + frow) * K + k0 + t * 32 + kb * 8);
    __builtin_amdgcn_sched_barrier(0);   // pin the B loads above the compute
    __syncthreads();   // drains vmcnt -> As valid

    #pragma unroll
    for (int t = 0; t < 2; t++) {
      v8s af[4];
      #pragma unroll
      for (int i = 0; i < 4; i++)
        af[i] = *(const v8s*)(&As[t][0] + (wm * 64 + i * 16 + frow) * 32 + kb * 8);
      #pragma unroll
      for (int i = 0; i < 4; i++)
        #pragma unroll
        for (int j = 0; j < 4; j++)
          acc[i][j] = __builtin_amdgcn_mfma_f32_16x16x32_bf16(af[i], bfr[t][j], acc[i][j], 0, 0, 0);
    }
  }

  // epilogue: C/D layout col=lane&15, row=(lane>>4)*4+reg  [m89-verified]
  const int crow = (lane >> 4) * 4, ccol = lane & 15;
  #pragma unroll
  for (int j = 0; j < 4; j++) {
    const int n = n0 + wn * 64 + j * 16 + ccol;
    const float bv = bias[n];
    #pragma unroll
    for (int i = 0; i < 4; i++) {
      const int mb = m0 + wm * 64 + i * 16 + crow;
      #pragma unroll
      for (int r2 = 0; r2 < 4; r2++)
        C[(size_t)(mb + r2) * N + n] = (uint16_t)f2bf_bits(acc[i][j][r2] + bv);
    }
  }
}

// ---------------- k_softmax_gather: row lse + gather (linear domain) ----------------
__global__ void k_softmax_gather(const uint16_t* __restrict__ logits, const int* __restrict__ target,
                                 const int* __restrict__ tlen, float* __restrict__ pext,
                                 int T, int V, int L) {
  const int row = blockIdx.x * 4 + (threadIdx.x >> 6);   // one wave per row
  const int lane = threadIdx.x & 63;
  const uint16_t* lrow = logits + (size_t)row * V;

  float xs[16];
  int cnt = 0;
  float mx = -INFINITY;
  for (int base = 0; base < V; base += 256) {
    const int idx = base + lane * 4;
    uint2 u = *(const uint2*)(lrow + idx);
    float4 v;
    v.x = bf2f(u.x & 0xFFFFu); v.y = bf2f(u.x >> 16);
    v.z = bf2f(u.y & 0xFFFFu); v.w = bf2f(u.y >> 16);
    xs[cnt] = v.x; xs[cnt + 1] = v.y; xs[cnt + 2] = v.z; xs[cnt + 3] = v.w; cnt += 4;
    mx = fmaxf(mx, fmaxf(fmaxf(v.x, v.y), fmaxf(v.z, v.w)));
  }
  #pragma unroll
  for (int off = 32; off; off >>= 1) mx = fmaxf(mx, __shfl_xor(mx, off, 64));
  float sum = 0.f;
  #pragma unroll
  for (int q = 0; q < 16; q++) { if (q < cnt) sum += exp2f((xs[q] - mx) * L2E); }
  #pragma unroll
  for (int off = 32; off; off >>= 1) sum += __shfl_xor(sum, off, 64);
  const float lse2 = mx * L2E + log2f(sum);

  const int bidx = row / T;
  const int Lb = tlen[bidx];
  const int S = 2 * Lb + 1;
  float* prow = pext + (size_t)row * SPAD;
  for (int s = lane; s < SPAD; s += 64) {
    float p = 0.f;
    if (s < S) {
      const int lbl = (s & 1) ? target[bidx * L + ((s - 1) >> 1)] : 0;
      p = exp2f(bf2f(lrow[lbl]) * L2E - lse2);
    }
    prow[s] = p;
  }
}

// ---------------- k_ctc: scaled linear-domain CTC forward, 1 wave per batch ----------------
__device__ __forceinline__ float wave_shr1(float x) {   // lane l <- lane l-1, lane0 <- 0
  return __int_as_float(__builtin_amdgcn_update_dpp(0, __float_as_int(x), 0x138, 0xf, 0xf, true));
}
__device__ __forceinline__ float wave_max_nonneg(float x) {
  x = fmaxf(x, __int_as_float(__builtin_amdgcn_update_dpp(0, __float_as_int(x), 0x111, 0xf, 0xf, true)));
  x = fmaxf(x, __int_as_float(__builtin_amdgcn_update_dpp(0, __float_as_int(x), 0x112, 0xf, 0xf, true)));
  x = fmaxf(x, __int_as_float(__builtin_amdgcn_update_dpp(0, __float_as_int(x), 0x114, 0xf, 0xf, true)));
  x = fmaxf(x, __int_as_float(__builtin_amdgcn_update_dpp(0, __float_as_int(x), 0x118, 0xf, 0xf, true)));
  x = fmaxf(x, __int_as_float(__builtin_amdgcn_update_dpp(0, __float_as_int(x), 0x142, 0xf, 0xf, true)));
  x = fmaxf(x, __int_as_float(__builtin_amdgcn_update_dpp(0, __float_as_int(x), 0x143, 0xf, 0xf, true)));
  return __int_as_float(__builtin_amdgcn_readlane(__float_as_int(x), 63));
}

__device__ __forceinline__ void load8(float4* __restrict__ p, float* __restrict__ p4,
                                      const float* __restrict__ pb, int t0, int lane) {
  #pragma unroll
  for (int k = 0; k < 8; k++) {
    const float* row = pb + (size_t)(t0 + k) * SPAD;
    p[k] = *(const float4*)(row + (lane << 2));
    p4[k] = row[256];               // wave-broadcast load
  }
}

__global__ __launch_bounds__(64, 1) void k_ctc(const float* __restrict__ pext,
                                               const int* __restrict__ target,
                                               const int* __restrict__ ilen,
                                               const int* __restrict__ tlen,
                                               float* __restrict__ out, int T, int L) {
  const int b = blockIdx.x;
  const int lane = threadIdx.x;          // 64 threads = 1 wave
  const int B = gridDim.x;
  const int Tb = ilen[b];
  const int Lb = tlen[b];
  const int S = 2 * Lb + 1;
  const int* tg = target + b * L;

  const int s1 = 4 * lane + 1, s3 = 4 * lane + 3;
  float sk1 = 0.f, sk3 = 0.f;
  if (s1 >= 3 && s1 < S) sk1 = (tg[(s1 - 1) >> 1] != tg[(s1 - 3) >> 1]) ? 1.f : 0.f;
  if (s3 >= 3 && s3 < S) sk3 = (tg[(s3 - 1) >> 1] != tg[(s3 - 3) >> 1]) ? 1.f : 0.f;

  const float* pb = pext + (size_t)b * T * SPAD;
  const float4 p0 = *(const float4*)(pb + (lane << 2));
  float a0 = (lane == 0) ? p0.x : 0.f;
  float a1 = (lane == 0) ? p0.y : 0.f;
  float a2 = 0.f, a3 = 0.f, a4 = 0.f;
  float log2C = 0.f;

  #define CTC_STEP(PP, P4) {                                            \
    const float pm3 = wave_shr1(a3);                                    \
    const float a255 = __int_as_float(__builtin_amdgcn_readlane(__float_as_int(a3), 63)); \
    const float n0v = (a0 + pm3) * (PP).x;                              \
    const float n1v = (a1 + a0 + sk1 * pm3) * (PP).y;                   \
    const float n2v = (a2 + a1) * (PP).z;                               \
    const float n3v = (a3 + a2 + sk3 * a1) * (PP).w;                    \
    const float n4v = (a4 + a255) * (P4);                               \
    a0 = n0v; a1 = n1v; a2 = n2v; a3 = n3v; a4 = n4v; }

  #define RENORM {                                                      \
    float m = fmaxf(fmaxf(fmaxf(a0, a1), fmaxf(a2, a3)), a4);           \
    m = wave_max_nonneg(m);                                             \
    const int e = (int)((__float_as_uint(m) >> 23) & 255u) - 127;       \
    const float scale = __uint_as_float((uint32_t)(127 - e) << 23);     \
    a0 *= scale; a1 *= scale; a2 *= scale; a3 *= scale; a4 *= scale;    \
    log2C += (float)e; }

  float4 Pa[8], Pb_[8], Pc[8], Pd[8];
  float Qa[8], Qb[8], Qc[8], Qd[8];
  int t0 = 1;
  bool done = false;
  load8(Pa, Qa, pb, t0, lane);
  load8(Pb_, Qb, pb, t0 + 8, lane);
  load8(Pc, Qc, pb, t0 + 16, lane);
  __builtin_amdgcn_sched_barrier(0);

  #define PHASE(LP, LQ, CP, CQ) {                                       \
    if (t0 + 8 <= Tb) {                                                 \
      load8(LP, LQ, pb, t0 + 24, lane);                                 \
      __builtin_amdgcn_sched_barrier(0);                                \
      _Pragma("unroll")                                                 \
      for (int k = 0; k < 8; k++) CTC_STEP(CP[k], CQ[k]);               \
      RENORM; t0 += 8;                                                  \
    } else {                                                            \
      _Pragma("unroll")                                                 \
      for (int k = 0; k < 8; k++) { if (t0 + k < Tb) CTC_STEP(CP[k], CQ[k]); } \
      RENORM; done = true;                                              \
    } }

  while (!done) {
    PHASE(Pd, Qd, Pa, Qa); if (done) break;
    PHASE(Pa, Qa, Pb_, Qb); if (done) break;
    PHASE(Pb_, Qb, Pc, Qc); if (done) break;
    PHASE(Pc, Qc, Pd, Qd);
  }

  __shared__ float abuf[257];
  abuf[4 * lane + 0] = a0; abuf[4 * lane + 1] = a1;
  abuf[4 * lane + 2] = a2; abuf[4 * lane + 3] = a3;
  if (lane == 63) abuf[256] = a4;
  __syncthreads();
  if (lane == 0) {
    const float ssum = abuf[2 * Lb - 1] + abuf[2 * Lb];
    const float ll = (log2f(ssum) + log2C) * LN2;
    float nll = -ll;
    if (!(nll < 1e29f)) nll = 0.f;                 // zero_infinity (also catches inf/nan)
    atomicAdd(out, nll / ((float)(Lb > 0 ? Lb : 1) * (float)B));
  }
}

// ---------------------------------------------------------------------------
extern "C" void kernel_launch(void* const* d_in, const int* in_sizes, int n_in,
                              void* d_out, int out_size, void* d_ws, size_t ws_size,
                              hipStream_t stream) {
  const float* x      = (const float*)d_in[0];
  const float* W      = (const float*)d_in[1];
  const float* bias   = (const float*)d_in[2];
  const int*  target  = (const int*)d_in[3];
  const int*  ilen    = (const int*)d_in[4];
  const int*  tlen    = (const int*)d_in[5];

  const int B = in_sizes[4];
  const int V = in_sizes[2];
  const int D = in_sizes[1] / V;
  const int T = in_sizes[0] / (B * D);
  const int L = in_sizes[3] / B;
  const int M = B * T;

  char* ws = (char*)d_ws;
  const size_t xb_bytes = (size_t)M * D * 2;
  const size_t wt_bytes = (size_t)V * D * 2;
  const size_t pext_bytes = (size_t)(M + PEXT_PAD_ROWS) * SPAD * 4;
  uint16_t* xb = (uint16_t*)ws;
  uint16_t* Wt = (uint16_t*)(ws + xb_bytes);
  uint16_t* logits = (uint16_t*)(ws + xb_bytes + wt_bytes);
  const size_t log_bytes = (size_t)M * V * 2;

  float* pext;
  if (pext_bytes <= xb_bytes + wt_bytes) {
    pext = (float*)ws;                 // overlay dead xb/Wt region after GEMM
  } else {
    pext = (float*)(ws + xb_bytes + wt_bytes + log_bytes);
  }

  const long long nx = (long long)M * D;
  const int nconv = (int)((nx / 8 + 255) / 256);
  const int ntrans = (V / 32) * (D / 32);
  k_prep<<<nconv + ntrans, 256, 0, stream>>>(x, xb, nx, W, Wt, D, V, (float*)d_out, nconv);
  k_gemm<<<dim3(M / 128, V / 128), 256, 0, stream>>>(xb, Wt, bias, logits, M, V, D);
  k_softmax_gather<<<M / 4, 256, 0, stream>>>(logits, target, tlen, pext, T, V, L);
  k_ctc<<<B, 64, 0, stream>>>(pext, target, ilen, tlen, (float*)d_out, T, L);
}

// Round 8
// 182.588 us; speedup vs baseline: 1.0263x; 1.0199x over previous
//
#include <hip/hip_runtime.h>
#include <cstdint>

// ---------------------------------------------------------------------------
// CTC loss pipeline:
//   k_prep : x fp32->bf16, W[D,V] -> Wt[V,D] bf16, zero d_out
//   k_gemm : BARRIER-FREE K-loop. Whole A-tile (64 rows x K) staged to LDS
//            once (1 barrier total); B fragments direct from L2-resident Wt;
//            16 k-iters of pure ds_read+load+MFMA.
//   k_softmax_gather : row lse + ext-label exp-gather -> pext (linear domain)
//   k_ctc  : 4-deep pipelined scaled linear-domain CTC forward, atomic mean.
// ---------------------------------------------------------------------------

#define SPAD 260                      // padded extended-state row (257 -> 260)
#define PEXT_PAD_ROWS 64              // prefetch overrun pad (loaded, never consumed)
#define ASTR 520                      // LDS A row stride, ushorts (512 + 8 pad -> 2-way banks, free)
#define L2E 1.4426950408889634f
#define LN2 0.6931471805599453f

typedef short v8s __attribute__((ext_vector_type(8)));
typedef float v4f __attribute__((ext_vector_type(4)));

__device__ __forceinline__ uint32_t f2bf_bits(float f) {
  uint32_t u = __float_as_uint(f);
  return (u + 0x7FFFu + ((u >> 16) & 1u)) >> 16;   // RNE
}
__device__ __forceinline__ float bf2f(uint32_t h) { return __uint_as_float(h << 16); }

// ---------------- k_prep: x fp32->bf16, W transpose->bf16, zero d_out ----------------
__global__ void k_prep(const float* __restrict__ x, uint16_t* __restrict__ xb, long long n,
                       const float* __restrict__ W, uint16_t* __restrict__ Wt, int D, int V,
                       float* __restrict__ out, int nconv) {
  if (blockIdx.x == 0 && threadIdx.x == 0) out[0] = 0.f;   // zero the atomic target
  if ((int)blockIdx.x < nconv) {
    long long i = ((long long)blockIdx.x * blockDim.x + threadIdx.x) * 8;
    if (i >= n) return;
    float4 a = *(const float4*)(x + i);
    float4 b = *(const float4*)(x + i + 4);
    uint4 o;
    o.x = f2bf_bits(a.x) | (f2bf_bits(a.y) << 16);
    o.y = f2bf_bits(a.z) | (f2bf_bits(a.w) << 16);
    o.z = f2bf_bits(b.x) | (f2bf_bits(b.y) << 16);
    o.w = f2bf_bits(b.z) | (f2bf_bits(b.w) << 16);
    *(uint4*)(xb + i) = o;
  } else {
    __shared__ float tile[32][33];
    const int bid2 = blockIdx.x - nconv;
    const int n0 = (bid2 % (V / 32)) * 32, k0 = (bid2 / (V / 32)) * 32;
    const int tx = threadIdx.x & 31, ty = threadIdx.x >> 5;   // (32,8)
    #pragma unroll
    for (int i = 0; i < 32; i += 8)
      tile[ty + i][tx] = W[(size_t)(k0 + ty + i) * V + n0 + tx];
    __syncthreads();
    #pragma unroll
    for (int i = 0; i < 32; i += 8)
      Wt[(size_t)(n0 + ty + i) * D + k0 + tx] = (uint16_t)f2bf_bits(tile[tx][ty + i]);
  }
}

// ---------------- k_gemm: barrier-free K-loop ----------------
// A:[M,K] bf16, Bt:[N,K] bf16 (=W^T), C:[M,N] bf16.
// Block: 64 rows x 256 cols, 4 waves (wave w -> cols n0+64w..+63).
// Requires M%64==0, N%256==0, K%32==0, K<=512 (LDS tile).
__global__ __launch_bounds__(256) void k_gemm(const uint16_t* __restrict__ A,
                                              const uint16_t* __restrict__ Bt,
                                              const float* __restrict__ bias,
                                              uint16_t* __restrict__ C, int M, int N, int K) {
  __shared__ uint16_t As[64 * ASTR];   // 66.5 KB
  const int tid = threadIdx.x, lane = tid & 63, wave = tid >> 6;
  const int m0 = blockIdx.x * 64, n0 = blockIdx.y * 256;
  const int frow = lane & 15, kb = lane >> 4;
  v4f acc[4][4] = {};

  // Stage the whole A-tile: issue i stages row i*4+wave (64 lanes x 16B = 1 row).
  // Wave-uniform LDS base (row*ASTR) + lane*16 -> global_load_lds-compatible
  // even with the padded stride.
  #pragma unroll
  for (int i = 0; i < 16; i++) {
    const int r = i * 4 + wave;
    const uint16_t* ga = A + (size_t)(m0 + r) * K + lane * 8;
    __builtin_amdgcn_global_load_lds(
        (const __attribute__((address_space(1))) void*)ga,
        (__attribute__((address_space(3))) void*)(As + r * ASTR + lane * 8), 16, 0, 0);
  }
  __syncthreads();   // the ONLY barrier

  const uint16_t* Bw = Bt + (size_t)(n0 + wave * 64) * K;
  #pragma unroll 2
  for (int k0 = 0; k0 < K; k0 += 32) {
    v8s bfr[4], af[4];
    #pragma unroll
    for (int j = 0; j < 4; j++)
      bfr[j] = *(const v8s*)(Bw + (size_t)(j * 16 + frow) * K + k0 + kb * 8);
    #pragma unroll
    for (int i = 0; i < 4; i++)
      af[i] = *(const v8s*)(As + (i * 16 + frow) * ASTR + k0 + kb * 8);
    #pragma unroll
    for (int i = 0; i < 4; i++)
      #pragma unroll
      for (int j = 0; j < 4; j++)
        acc[i][j] = __builtin_amdgcn_mfma_f32_16x16x32_bf16(af[i], bfr[j], acc[i][j], 0, 0, 0);
  }

  // epilogue: C/D layout col=lane&15, row=(lane>>4)*4+reg  [m89-verified]
  const int crow = (lane >> 4) * 4, ccol = lane & 15;
  #pragma unroll
  for (int j = 0; j < 4; j++) {
    const int n = n0 + wave * 64 + j * 16 + ccol;
    const float bv = bias[n];
    #pragma unroll
    for (int i = 0; i < 4; i++) {
      const int mb = m0 + i * 16 + crow;
      #pragma unroll
      for (int r2 = 0; r2 < 4; r2++)
        C[(size_t)(mb + r2) * N + n] = (uint16_t)f2bf_bits(acc[i][j][r2] + bv);
    }
  }
}

// ---------------- k_softmax_gather: row lse + gather (linear domain) ----------------
__global__ void k_softmax_gather(const uint16_t* __restrict__ logits, const int* __restrict__ target,
                                 const int* __restrict__ tlen, float* __restrict__ pext,
                                 int T, int V, int L) {
  const int row = blockIdx.x * 4 + (threadIdx.x >> 6);   // one wave per row
  const int lane = threadIdx.x & 63;
  const uint16_t* lrow = logits + (size_t)row * V;

  float xs[16];
  int cnt = 0;
  float mx = -INFINITY;
  for (int base = 0; base < V; base += 256) {
    const int idx = base + lane * 4;
    uint2 u = *(const uint2*)(lrow + idx);
    float4 v;
    v.x = bf2f(u.x & 0xFFFFu); v.y = bf2f(u.x >> 16);
    v.z = bf2f(u.y & 0xFFFFu); v.w = bf2f(u.y >> 16);
    xs[cnt] = v.x; xs[cnt + 1] = v.y; xs[cnt + 2] = v.z; xs[cnt + 3] = v.w; cnt += 4;
    mx = fmaxf(mx, fmaxf(fmaxf(v.x, v.y), fmaxf(v.z, v.w)));
  }
  #pragma unroll
  for (int off = 32; off; off >>= 1) mx = fmaxf(mx, __shfl_xor(mx, off, 64));
  float sum = 0.f;
  #pragma unroll
  for (int q = 0; q < 16; q++) { if (q < cnt) sum += exp2f((xs[q] - mx) * L2E); }
  #pragma unroll
  for (int off = 32; off; off >>= 1) sum += __shfl_xor(sum, off, 64);
  const float lse2 = mx * L2E + log2f(sum);

  const int bidx = row / T;
  const int Lb = tlen[bidx];
  const int S = 2 * Lb + 1;
  float* prow = pext + (size_t)row * SPAD;
  for (int s = lane; s < SPAD; s += 64) {
    float p = 0.f;
    if (s < S) {
      const int lbl = (s & 1) ? target[bidx * L + ((s - 1) >> 1)] : 0;
      p = exp2f(bf2f(lrow[lbl]) * L2E - lse2);
    }
    prow[s] = p;
  }
}

// ---------------- k_ctc: scaled linear-domain CTC forward, 1 wave per batch ----------------
__device__ __forceinline__ float wave_shr1(float x) {   // lane l <- lane l-1, lane0 <- 0
  return __int_as_float(__builtin_amdgcn_update_dpp(0, __float_as_int(x), 0x138, 0xf, 0xf, true));
}
__device__ __forceinline__ float wave_max_nonneg(float x) {
  x = fmaxf(x, __int_as_float(__builtin_amdgcn_update_dpp(0, __float_as_int(x), 0x111, 0xf, 0xf, true)));
  x = fmaxf(x, __int_as_float(__builtin_amdgcn_update_dpp(0, __float_as_int(x), 0x112, 0xf, 0xf, true)));
  x = fmaxf(x, __int_as_float(__builtin_amdgcn_update_dpp(0, __float_as_int(x), 0x114, 0xf, 0xf, true)));
  x = fmaxf(x, __int_as_float(__builtin_amdgcn_update_dpp(0, __float_as_int(x), 0x118, 0xf, 0xf, true)));
  x = fmaxf(x, __int_as_float(__builtin_amdgcn_update_dpp(0, __float_as_int(x), 0x142, 0xf, 0xf, true)));
  x = fmaxf(x, __int_as_float(__builtin_amdgcn_update_dpp(0, __float_as_int(x), 0x143, 0xf, 0xf, true)));
  return __int_as_float(__builtin_amdgcn_readlane(__float_as_int(x), 63));
}

__device__ __forceinline__ void load8(float4* __restrict__ p, float* __restrict__ p4,
                                      const float* __restrict__ pb, int t0, int lane) {
  #pragma unroll
  for (int k = 0; k < 8; k++) {
    const float* row = pb + (size_t)(t0 + k) * SPAD;
    p[k] = *(const float4*)(row + (lane << 2));
    p4[k] = row[256];               // wave-broadcast load
  }
}

__global__ __launch_bounds__(64, 1) void k_ctc(const float* __restrict__ pext,
                                               const int* __restrict__ target,
                                               const int* __restrict__ ilen,
                                               const int* __restrict__ tlen,
                                               float* __restrict__ out, int T, int L) {
  const int b = blockIdx.x;
  const int lane = threadIdx.x;          // 64 threads = 1 wave
  const int B = gridDim.x;
  const int Tb = ilen[b];
  const int Lb = tlen[b];
  const int S = 2 * Lb + 1;
  const int* tg = target + b * L;

  const int s1 = 4 * lane + 1, s3 = 4 * lane + 3;
  float sk1 = 0.f, sk3 = 0.f;
  if (s1 >= 3 && s1 < S) sk1 = (tg[(s1 - 1) >> 1] != tg[(s1 - 3) >> 1]) ? 1.f : 0.f;
  if (s3 >= 3 && s3 < S) sk3 = (tg[(s3 - 1) >> 1] != tg[(s3 - 3) >> 1]) ? 1.f : 0.f;

  const float* pb = pext + (size_t)b * T * SPAD;
  const float4 p0 = *(const float4*)(pb + (lane << 2));
  float a0 = (lane == 0) ? p0.x : 0.f;
  float a1 = (lane == 0) ? p0.y : 0.f;
  float a2 = 0.f, a3 = 0.f, a4 = 0.f;
  float log2C = 0.f;

  #define CTC_STEP(PP, P4) {                                            \
    const float pm3 = wave_shr1(a3);                                    \
    const float a255 = __int_as_float(__builtin_amdgcn_readlane(__float_as_int(a3), 63)); \
    const float n0v = (a0 + pm3) * (PP).x;                              \
    const float n1v = (a1 + a0 + sk1 * pm3) * (PP).y;                   \
    const float n2v = (a2 + a1) * (PP).z;                               \
    const float n3v = (a3 + a2 + sk3 * a1) * (PP).w;                    \
    const float n4v = (a4 + a255) * (P4);                               \
    a0 = n0v; a1 = n1v; a2 = n2v; a3 = n3v; a4 = n4v; }

  #define RENORM {                                                      \
    float m = fmaxf(fmaxf(fmaxf(a0, a1), fmaxf(a2, a3)), a4);           \
    m = wave_max_nonneg(m);                                             \
    const int e = (int)((__float_as_uint(m) >> 23) & 255u) - 127;       \
    const float scale = __uint_as_float((uint32_t)(127 - e) << 23);     \
    a0 *= scale; a1 *= scale; a2 *= scale; a3 *= scale; a4 *= scale;    \
    log2C += (float)e; }

  float4 Pa[8], Pb_[8], Pc[8], Pd[8];
  float Qa[8], Qb[8], Qc[8], Qd[8];
  int t0 = 1;
  bool done = false;
  load8(Pa, Qa, pb, t0, lane);
  load8(Pb_, Qb, pb, t0 + 8, lane);
  load8(Pc, Qc, pb, t0 + 16, lane);
  __builtin_amdgcn_sched_barrier(0);

  #define PHASE(LP, LQ, CP, CQ) {                                       \
    if (t0 + 8 <= Tb) {                                                 \
      load8(LP, LQ, pb, t0 + 24, lane);                                 \
      __builtin_amdgcn_sched_barrier(0);                                \
      _Pragma("unroll")                                                 \
      for (int k = 0; k < 8; k++) CTC_STEP(CP[k], CQ[k]);               \
      RENORM; t0 += 8;                                                  \
    } else {                                                            \
      _Pragma("unroll")                                                 \
      for (int k = 0; k < 8; k++) { if (t0 + k < Tb) CTC_STEP(CP[k], CQ[k]); } \
      RENORM; done = true;                                              \
    } }

  while (!done) {
    PHASE(Pd, Qd, Pa, Qa); if (done) break;
    PHASE(Pa, Qa, Pb_, Qb); if (done) break;
    PHASE(Pb_, Qb, Pc, Qc); if (done) break;
    PHASE(Pc, Qc, Pd, Qd);
  }

  __shared__ float abuf[257];
  abuf[4 * lane + 0] = a0; abuf[4 * lane + 1] = a1;
  abuf[4 * lane + 2] = a2; abuf[4 * lane + 3] = a3;
  if (lane == 63) abuf[256] = a4;
  __syncthreads();
  if (lane == 0) {
    const float ssum = abuf[2 * Lb - 1] + abuf[2 * Lb];
    const float ll = (log2f(ssum) + log2C) * LN2;
    float nll = -ll;
    if (!(nll < 1e29f)) nll = 0.f;                 // zero_infinity (also catches inf/nan)
    atomicAdd(out, nll / ((float)(Lb > 0 ? Lb : 1) * (float)B));
  }
}

// ---------------------------------------------------------------------------
extern "C" void kernel_launch(void* const* d_in, const int* in_sizes, int n_in,
                              void* d_out, int out_size, void* d_ws, size_t ws_size,
                              hipStream_t stream) {
  const float* x      = (const float*)d_in[0];
  const float* W      = (const float*)d_in[1];
  const float* bias   = (const float*)d_in[2];
  const int*  target  = (const int*)d_in[3];
  const int*  ilen    = (const int*)d_in[4];
  const int*  tlen    = (const int*)d_in[5];

  const int B = in_sizes[4];
  const int V = in_sizes[2];
  const int D = in_sizes[1] / V;
  const int T = in_sizes[0] / (B * D);
  const int L = in_sizes[3] / B;
  const int M = B * T;

  char* ws = (char*)d_ws;
  const size_t xb_bytes = (size_t)M * D * 2;
  const size_t wt_bytes = (size_t)V * D * 2;
  const size_t pext_bytes = (size_t)(M + PEXT_PAD_ROWS) * SPAD * 4;
  uint16_t* xb = (uint16_t*)ws;
  uint16_t* Wt = (uint16_t*)(ws + xb_bytes);
  uint16_t* logits = (uint16_t*)(ws + xb_bytes + wt_bytes);
  const size_t log_bytes = (size_t)M * V * 2;

  float* pext;
  if (pext_bytes <= xb_bytes + wt_bytes) {
    pext = (float*)ws;                 // overlay dead xb/Wt region after GEMM
  } else {
    pext = (float*)(ws + xb_bytes + wt_bytes + log_bytes);
  }

  const long long nx = (long long)M * D;
  const int nconv = (int)((nx / 8 + 255) / 256);
  const int ntrans = (V / 32) * (D / 32);
  k_prep<<<nconv + ntrans, 256, 0, stream>>>(x, xb, nx, W, Wt, D, V, (float*)d_out, nconv);
  k_gemm<<<dim3(M / 64, V / 256), 256, 0, stream>>>(xb, Wt, bias, logits, M, V, D);
  k_softmax_gather<<<M / 4, 256, 0, stream>>>(logits, target, tlen, pext, T, V, L);
  k_ctc<<<B, 64, 0, stream>>>(pext, target, ilen, tlen, (float*)d_out, T, L);
}